// Round 4
// baseline (181.304 us; speedup 1.0000x reference)
//
#include <hip/hip_runtime.h>
#include <hip/hip_bf16.h>
#include <hip/hip_fp16.h>

// Problem constants (B=8, T=4096, Din=Dout=256, WINDOW=2)
#define BDIM 8
#define TDIM 4096
#define DDIM 256
#define MDIM (BDIM * TDIM)      // 32768
#define NCHUNK 256              // chunks along T for the parallel scan
#define LCHUNK (TDIM / NCHUNK)  // 16

typedef _Float16 f16x8 __attribute__((ext_vector_type(8)));
typedef _Float16 f16x4 __attribute__((ext_vector_type(4)));
typedef float f32x4 __attribute__((ext_vector_type(4)));

__device__ __forceinline__ float sigmoid_(float x) {
    return 1.0f / (1.0f + __expf(-x));
}
__device__ __forceinline__ float tanh_(float x) {
    return 2.0f / (1.0f + __expf(-2.0f * x)) - 1.0f;
}

__device__ __forceinline__ f16x8 cvt8(const float4 a, const float4 b) {
    f16x8 r;
    r[0] = (_Float16)a.x; r[1] = (_Float16)a.y;
    r[2] = (_Float16)a.z; r[3] = (_Float16)a.w;
    r[4] = (_Float16)b.x; r[5] = (_Float16)b.y;
    r[6] = (_Float16)b.z; r[7] = (_Float16)b.w;
    return r;
}

// ---------------------------------------------------------------------------
// W[g][w][kin][n] fp32 -> Wt[g][n][w*256+kin] f16 (contiguous in k).
// ---------------------------------------------------------------------------
__global__ __launch_bounds__(256) void convert_w(
    const float* __restrict__ Wz, const float* __restrict__ Wf,
    const float* __restrict__ Wo, _Float16* __restrict__ Wt) {
    const int idx = blockIdx.x * 256 + threadIdx.x;  // < 3*2*256*256
    const int n = idx & 255;
    const int kin = (idx >> 8) & 255;
    const int w = (idx >> 16) & 1;
    const int g = idx >> 17;
    const float* W = (g == 0) ? Wz : (g == 1) ? Wf : Wo;
    const float v = W[(size_t)w * 65536 + (size_t)kin * 256 + n];
    Wt[((size_t)g * 256 + n) * 512 + w * 256 + kin] = (_Float16)v;
}

// ---------------------------------------------------------------------------
// MFMA GEMM with REGISTER-staged double-buffer pipeline.
//   Per iteration: barrier -> issue global loads for tile it+1 into VGPRs
//   -> ds_read frags + 16 MFMA (overlaps the loads) -> cvt+ds_write regs
//   into the other LDS buffer. The vmcnt wait lands at the ds_write, a full
//   MFMA phase after issue, so the barrier's vmcnt(0) drain is already
//   satisfied — unlike the global_load_lds structure (m99/m100 trap).
// A is read directly from fp32 x (window-2 conv linearized: row m=(b,t),
// k<256 -> x[b][t-1], k>=256 -> x[b][t]; zero row at t-1<0), converted to
// f16 in registers. 128x128 tile, 4 waves, 4x4 frags of 16x16x32 f16.
// Outputs z,f,o stored f16 via LDS-repacked 16 B/lane stores.
// ---------------------------------------------------------------------------
__global__ __launch_bounds__(256) void gates_mfma(
    const float* __restrict__ x, const _Float16* __restrict__ Wt,
    const float* __restrict__ bz, const float* __restrict__ bfv,
    const float* __restrict__ bo,
    _Float16* __restrict__ zbuf, _Float16* __restrict__ fbuf,
    _Float16* __restrict__ obuf) {
    const int gate = blockIdx.z;
    const int m0 = blockIdx.x * 128;
    const int n0 = blockIdx.y * 128;
    const int tid = threadIdx.x;
    const int lane = tid & 63;
    const int wave = tid >> 6;
    const int wr = wave >> 1;  // wave row (0..1)
    const int wc = wave & 1;   // wave col (0..1)

    // [0,16384): buf0 = A(8K) | B(8K); [16384,32768): buf1.
    // Epilogue reuses [0,40960) as 4 x 10240 B per-wave repack tiles.
    __shared__ __align__(16) char smem[40960];

    // Staging map: thread tid covers LDS row tid>>1, 16 halves at (tid&1)*16.
    const int arow = tid >> 1;        // 0..127
    const int ac = (tid & 1) * 16;    // half offset in the 32-wide k tile

    const int b = m0 >> 12;
    const int t0 = m0 & (TDIM - 1);

    const float* xb = x + (size_t)b * TDIM * DDIM;
    const _Float16* pB = Wt + ((size_t)gate * 256 + n0 + arow) * 512 + ac;

    float4 ga0, ga1, ga2, ga3;
    int4 gb0, gb1;

#define LOAD_TILE(k0)                                                        \
    {                                                                        \
        const int half = (k0) >> 8;                                          \
        const int kin = (k0) & 255;                                          \
        const int t = t0 + arow - 1 + half;                                  \
        if (t >= 0) {                                                        \
            const float* src = xb + (size_t)t * DDIM + kin + ac;             \
            ga0 = *(const float4*)(src);                                     \
            ga1 = *(const float4*)(src + 4);                                 \
            ga2 = *(const float4*)(src + 8);                                 \
            ga3 = *(const float4*)(src + 12);                                \
        } else {                                                             \
            ga0 = ga1 = ga2 = ga3 = make_float4(0.f, 0.f, 0.f, 0.f);         \
        }                                                                    \
        gb0 = *(const int4*)(pB + (k0));                                     \
        gb1 = *(const int4*)(pB + (k0) + 8);                                 \
    }

#define STORE_TILE(bufp)                                                     \
    {                                                                        \
        _Float16* Ad = (_Float16*)(bufp);                                    \
        _Float16* Bd = (_Float16*)((char*)(bufp) + 8192);                    \
        *(f16x8*)(Ad + arow * 32 + ac) = cvt8(ga0, ga1);                     \
        *(f16x8*)(Ad + arow * 32 + ac + 8) = cvt8(ga2, ga3);                 \
        *(int4*)(Bd + arow * 32 + ac) = gb0;                                 \
        *(int4*)(Bd + arow * 32 + ac + 8) = gb1;                             \
    }

    f32x4 acc[4][4] = {};
    const int am = lane & 15;
    const int kq = (lane >> 4) * 8;  // halves

    // Prologue: tile 0 -> regs -> buf0.
    LOAD_TILE(0);
    STORE_TILE(smem);

    for (int it = 0; it < 16; ++it) {
        __syncthreads();  // buf[it&1] writes visible; vmcnt already drained
        const int cur = it & 1;
        if (it < 15) LOAD_TILE((it + 1) * 32);  // async; consumed at ds_write

        const _Float16* Ab = (const _Float16*)(smem + cur * 16384);
        const _Float16* Bb = (const _Float16*)(smem + cur * 16384 + 8192);

        f16x8 a[4], bb[4];
#pragma unroll
        for (int i = 0; i < 4; ++i)
            a[i] = *(const f16x8*)(Ab + (wr * 64 + i * 16 + am) * 32 + kq);
#pragma unroll
        for (int j = 0; j < 4; ++j)
            bb[j] = *(const f16x8*)(Bb + (wc * 64 + j * 16 + am) * 32 + kq);
#pragma unroll
        for (int i = 0; i < 4; ++i)
#pragma unroll
            for (int j = 0; j < 4; ++j)
                acc[i][j] = __builtin_amdgcn_mfma_f32_16x16x32_f16(
                    a[i], bb[j], acc[i][j], 0, 0, 0);

        if (it < 15) STORE_TILE(smem + (cur ^ 1) * 16384);  // vmcnt wait here
    }

    __syncthreads();  // all K-loop LDS reads done before epilogue reuse

    // Epilogue: activation into per-wave LDS tile (stride 80 halves), then
    // 16 B/lane contiguous global stores.
    const float* bias = (gate == 0) ? bz : (gate == 1) ? bfv : bo;
    _Float16* outp = (gate == 0) ? zbuf : (gate == 1) ? fbuf : obuf;
    _Float16* eb = (_Float16*)smem + wave * 5120;  // 64 x 80 halves
    const int rq = (lane >> 4) * 4;
#pragma unroll
    for (int j = 0; j < 4; ++j) {
        const int gc = n0 + wc * 64 + j * 16 + am;
        const float bj = bias[gc];
#pragma unroll
        for (int i = 0; i < 4; ++i) {
            f32x4 v = acc[i][j];
#pragma unroll
            for (int r = 0; r < 4; ++r) {
                const float val = v[r] + bj;
                const float act = (gate == 0) ? tanh_(val) : sigmoid_(val);
                eb[(i * 16 + rq + r) * 80 + j * 16 + am] = (_Float16)act;
            }
        }
    }
    __syncthreads();

    const int rrow = lane >> 3;       // 0..7
    const int rcol = (lane & 7) * 8;  // halves
#pragma unroll
    for (int rr = 0; rr < 8; ++rr) {
        const int row = rr * 8 + rrow;
        f16x8 v = *(const f16x8*)(eb + row * 80 + rcol);
        const size_t gm = (size_t)(m0 + wr * 64 + row);
        *(f16x8*)(outp + gm * DDIM + n0 + wc * 64 + rcol) = v;
    }
#undef LOAD_TILE
#undef STORE_TILE
}

// ---------------------------------------------------------------------------
// Scan pass 1: per-chunk aggregates over LCHUNK steps from c=0; A = prod(f).
// 65536 lanes -> 256 blocks (all CUs). 16 B f16 vector loads.
// ---------------------------------------------------------------------------
__global__ __launch_bounds__(256) void scan_pass1(
    const _Float16* __restrict__ zbuf, const _Float16* __restrict__ fbuf,
    float* __restrict__ aggA, float* __restrict__ aggB) {
    const int idx = blockIdx.x * 256 + threadIdx.x;  // < B*NCHUNK*32 = 65536
    const int d8 = idx & 31;
    const int chunk = (idx >> 5) & (NCHUNK - 1);
    const int b = idx >> 13;

    const size_t row0 = (size_t)b * TDIM + (size_t)chunk * LCHUNK;
    const int4* zp = (const int4*)zbuf + row0 * 32 + d8;
    const int4* fp = (const int4*)fbuf + row0 * 32 + d8;

    float A[8], c[8];
#pragma unroll
    for (int e = 0; e < 8; ++e) { A[e] = 1.0f; c[e] = 0.0f; }

#pragma unroll
    for (int i = 0; i < LCHUNK; ++i) {
        int4 fv = *fp;
        int4 zv = *zp;
        const _Float16* fh = (const _Float16*)&fv;
        const _Float16* zh = (const _Float16*)&zv;
#pragma unroll
        for (int e = 0; e < 8; ++e) {
            const float f = (float)fh[e];
            const float z = (float)zh[e];
            A[e] *= f;
            c[e] = f * c[e] + (1.0f - f) * z;
        }
        fp += 32;
        zp += 32;
    }
    ((float4*)aggA)[(size_t)idx * 2 + 0] = make_float4(A[0], A[1], A[2], A[3]);
    ((float4*)aggA)[(size_t)idx * 2 + 1] = make_float4(A[4], A[5], A[6], A[7]);
    ((float4*)aggB)[(size_t)idx * 2 + 0] = make_float4(c[0], c[1], c[2], c[3]);
    ((float4*)aggB)[(size_t)idx * 2 + 1] = make_float4(c[4], c[5], c[6], c[7]);
}

// ---------------------------------------------------------------------------
// Carry scan across chunks: one thread per (b,d) = 2048 threads, unroll-8
// batched loads (16 outstanding) to hide latency over 256 serial chunks.
// agg layout: [b][chunk][d].
// ---------------------------------------------------------------------------
__global__ __launch_bounds__(256) void carry_scan(
    const float* __restrict__ aggA, const float* __restrict__ aggB,
    float* __restrict__ carry) {
    const int g = blockIdx.x * 256 + threadIdx.x;  // < B*D = 2048
    const int d = g & 255;
    const int b = g >> 8;
    const size_t base = (size_t)b * NCHUNK * 256 + d;

    float c = 0.0f;
    for (int ch0 = 0; ch0 < NCHUNK; ch0 += 8) {
        float A[8], Bv[8];
#pragma unroll
        for (int u = 0; u < 8; ++u) {
            const size_t p = base + (size_t)(ch0 + u) * 256;
            A[u] = aggA[p];
            Bv[u] = aggB[p];
        }
#pragma unroll
        for (int u = 0; u < 8; ++u) {
            const size_t p = base + (size_t)(ch0 + u) * 256;
            carry[p] = c;
            c = A[u] * c + Bv[u];
        }
    }
}

// ---------------------------------------------------------------------------
// Scan pass 2: replay chunk with true carry; h = o*c -> fp32 out.
// z,f,o all f16 (16 B vector loads); out written as 2x float4.
// ---------------------------------------------------------------------------
__global__ __launch_bounds__(256) void scan_pass2(
    const _Float16* __restrict__ zbuf, const _Float16* __restrict__ fbuf,
    const _Float16* __restrict__ obuf, const float* __restrict__ carry,
    float* __restrict__ out) {
    const int idx = blockIdx.x * 256 + threadIdx.x;  // < 65536
    const int d8 = idx & 31;
    const int chunk = (idx >> 5) & (NCHUNK - 1);
    const int b = idx >> 13;

    float c[8];
    float4 c0 = ((const float4*)carry)[(size_t)idx * 2];
    float4 c1 = ((const float4*)carry)[(size_t)idx * 2 + 1];
    c[0] = c0.x; c[1] = c0.y; c[2] = c0.z; c[3] = c0.w;
    c[4] = c1.x; c[5] = c1.y; c[6] = c1.z; c[7] = c1.w;

    const size_t row0 = (size_t)b * TDIM + (size_t)chunk * LCHUNK;
    const int4* zp = (const int4*)zbuf + row0 * 32 + d8;
    const int4* fp = (const int4*)fbuf + row0 * 32 + d8;
    const int4* op = (const int4*)obuf + row0 * 32 + d8;
    float4* hp = (float4*)out + row0 * 64 + d8 * 2;

#pragma unroll
    for (int i = 0; i < LCHUNK; ++i) {
        int4 fv = *fp;
        int4 zv = *zp;
        int4 ov = *op;
        const _Float16* fh = (const _Float16*)&fv;
        const _Float16* zh = (const _Float16*)&zv;
        const _Float16* oh = (const _Float16*)&ov;
        float h[8];
#pragma unroll
        for (int e = 0; e < 8; ++e) {
            const float f = (float)fh[e];
            const float z = (float)zh[e];
            c[e] = f * c[e] + (1.0f - f) * z;
            h[e] = (float)oh[e] * c[e];
        }
        hp[0] = make_float4(h[0], h[1], h[2], h[3]);
        hp[1] = make_float4(h[4], h[5], h[6], h[7]);
        fp += 32;
        zp += 32;
        op += 32;
        hp += 64;
    }
}

extern "C" void kernel_launch(void* const* d_in, const int* in_sizes, int n_in,
                              void* d_out, int out_size, void* d_ws,
                              size_t ws_size, hipStream_t stream) {
    const float* x = (const float*)d_in[0];
    const float* Wz = (const float*)d_in[1];
    const float* Wf = (const float*)d_in[2];
    const float* Wo = (const float*)d_in[3];
    const float* bz = (const float*)d_in[4];
    const float* bfv = (const float*)d_in[5];
    const float* bo = (const float*)d_in[6];
    float* out = (float*)d_out;

    // Workspace (bytes): Wt 0.79M | z 16.78M | f 16.78M | o 16.78M |
    // aggA 2M | aggB 2M | carry 2M   -> ~57.9 MB
    char* p = (char*)d_ws;
    _Float16* Wt = (_Float16*)p;    p += (size_t)3 * 256 * 512 * 2;
    _Float16* zbuf = (_Float16*)p;  p += (size_t)MDIM * DDIM * 2;
    _Float16* fbuf = (_Float16*)p;  p += (size_t)MDIM * DDIM * 2;
    _Float16* obuf = (_Float16*)p;  p += (size_t)MDIM * DDIM * 2;
    float* aggA = (float*)p;        p += (size_t)BDIM * NCHUNK * DDIM * 4;
    float* aggB = (float*)p;        p += (size_t)BDIM * NCHUNK * DDIM * 4;
    float* carry = (float*)p;

    convert_w<<<(3 * 2 * 256 * 256) / 256, 256, 0, stream>>>(Wz, Wf, Wo, Wt);

    gates_mfma<<<dim3(MDIM / 128, DDIM / 128, 3), 256, 0, stream>>>(
        x, Wt, bz, bfv, bo, zbuf, fbuf, obuf);

    scan_pass1<<<(BDIM * NCHUNK * 32) / 256, 256, 0, stream>>>(zbuf, fbuf,
                                                               aggA, aggB);
    carry_scan<<<(BDIM * DDIM) / 256, 256, 0, stream>>>(aggA, aggB, carry);
    scan_pass2<<<(BDIM * NCHUNK * 32) / 256, 256, 0, stream>>>(zbuf, fbuf,
                                                               obuf, carry, out);
}